// Round 1
// 734.595 us; speedup vs baseline: 1.1598x; 1.1598x over previous
//
#include <hip/hip_runtime.h>
#include <hip/hip_bf16.h>

#define NN 100000
#define FIN 512
#define H1D 64
#define H2D 128
#define CD 40
#define GP 64           // g3 padded row (bf16) -> one 128B line
#define BNEPS 1e-5f

#define BSHIFT 9
#define BSZ 512
#define NB 196          // ceil(NN / 512)
#define CHUNK 8192      // edges per scatter block

typedef __attribute__((ext_vector_type(8))) short bf16x8;
typedef __attribute__((ext_vector_type(4))) float f32x4;

__device__ __forceinline__ float bf2f(ushort u) {
    union { uint i; float f; } v; v.i = ((uint)u) << 16; return v.f;
}
__device__ __forceinline__ ushort f2bf(float f) {
    union { float f; uint i; } v; v.f = f;
    uint x = v.i;
    return (ushort)((x + 0x7fffu + ((x >> 16) & 1u)) >> 16);
}

// unpack 8 bf16 (one 16B row chunk) and accumulate into a[0..7]
__device__ __forceinline__ void acc8(float* a, uint4 v) {
    a[0] += bf2f((ushort)(v.x & 0xffff)); a[1] += bf2f((ushort)(v.x >> 16));
    a[2] += bf2f((ushort)(v.y & 0xffff)); a[3] += bf2f((ushort)(v.y >> 16));
    a[4] += bf2f((ushort)(v.z & 0xffff)); a[5] += bf2f((ushort)(v.z >> 16));
    a[6] += bf2f((ushort)(v.w & 0xffff)); a[7] += bf2f((ushort)(v.w >> 16));
}

// ---------------- graph preprocessing: bucketed CSR build ----------------

__global__ __launch_bounds__(256) void bhist_k(const int* __restrict__ dst, int E,
                                               int* __restrict__ bcount) {
    __shared__ int h[NB];
    for (int i = threadIdx.x; i < NB; i += 256) h[i] = 0;
    __syncthreads();
    int i = blockIdx.x * blockDim.x + threadIdx.x;
    int st = gridDim.x * blockDim.x;
    for (; i < E; i += st) atomicAdd(&h[dst[i] >> BSHIFT], 1);
    __syncthreads();
    for (int j = threadIdx.x; j < NB; j += 256)
        if (h[j]) atomicAdd(&bcount[j], h[j]);
}

__global__ __launch_bounds__(256) void bscan_k(const int* __restrict__ bcount,
                                               int* __restrict__ bstart,
                                               int* __restrict__ bcursor) {
    __shared__ int sh[NB];
    int tid = threadIdx.x;
    if (tid < NB) sh[tid] = bcount[tid];
    __syncthreads();
    for (int off = 1; off < NB; off <<= 1) {
        int v = (tid < NB && tid >= off) ? sh[tid - off] : 0;
        __syncthreads();
        if (tid < NB) sh[tid] += v;
        __syncthreads();
    }
    if (tid < NB) {
        int s = tid ? sh[tid - 1] : 0;
        bstart[tid] = s;
        bcursor[tid] = s;
    }
    if (tid == 0) bstart[NB] = sh[NB - 1];
}

__global__ __launch_bounds__(256) void bscatter_k(const int* __restrict__ src,
                                                  const int* __restrict__ dst, int E,
                                                  int* __restrict__ bcursor,
                                                  int* __restrict__ ebuf) {
    __shared__ int hist[NB];
    __shared__ int loff[NB];
    __shared__ int lcur[NB];
    __shared__ int gbase[NB];
    __shared__ int sbuf[CHUNK];
    int tid = threadIdx.x;
    int e0 = blockIdx.x * CHUNK;
    int e1 = e0 + CHUNK; if (e1 > E) e1 = E;

    for (int i = tid; i < NB; i += 256) hist[i] = 0;
    __syncthreads();
    for (int i = e0 + tid; i < e1; i += 256) atomicAdd(&hist[dst[i] >> BSHIFT], 1);
    __syncthreads();
    int v = (tid < NB) ? hist[tid] : 0;
    __syncthreads();
    if (tid < NB) loff[tid] = v;
    __syncthreads();
    for (int off = 1; off < NB; off <<= 1) {
        int u = (tid < NB && tid >= off) ? loff[tid - off] : 0;
        __syncthreads();
        if (tid < NB) loff[tid] += u;
        __syncthreads();
    }
    if (tid < NB) {
        int excl = loff[tid] - v;
        loff[tid] = excl;
        lcur[tid] = excl;
        gbase[tid] = (v > 0) ? atomicAdd(&bcursor[tid], v) : 0;
    }
    __syncthreads();
    for (int i = e0 + tid; i < e1; i += 256) {
        int d = dst[i];
        int b = d >> BSHIFT;
        int pos = atomicAdd(&lcur[b], 1);
        sbuf[pos] = (src[i] << BSHIFT) | (d & (BSZ - 1));
    }
    __syncthreads();
    int wave = tid >> 6, lane = tid & 63;
    for (int b = wave; b < NB; b += 4) {
        int cnt = (b + 1 < NB ? loff[b + 1] : (e1 - e0)) - loff[b];
        int s0 = loff[b], d0 = gbase[b];
        for (int k = lane; k < cnt; k += 64) ebuf[d0 + k] = sbuf[s0 + k];
    }
}

__global__ __launch_bounds__(256) void bcsr_k(const int* __restrict__ ebuf,
                                              const int* __restrict__ bstart,
                                              int* __restrict__ rowstart,
                                              float* __restrict__ dinv,
                                              int* __restrict__ csr, int E) {
    __shared__ int ldeg[BSZ];
    __shared__ int lcur[BSZ];
    __shared__ int s2[256];
    int b = blockIdx.x, tid = threadIdx.x;
    int node0 = b << BSHIFT;
    int es = bstart[b], ee = bstart[b + 1];
    ldeg[tid] = 0; ldeg[tid + 256] = 0;
    __syncthreads();
    for (int i = es + tid; i < ee; i += 256) atomicAdd(&ldeg[ebuf[i] & (BSZ - 1)], 1);
    __syncthreads();
    int a0 = ldeg[2 * tid], a1 = ldeg[2 * tid + 1];
    s2[tid] = a0 + a1;
    __syncthreads();
    for (int off = 1; off < 256; off <<= 1) {
        int u = (tid >= off) ? s2[tid - off] : 0;
        __syncthreads();
        s2[tid] += u;
        __syncthreads();
    }
    int base2 = tid ? s2[tid - 1] : 0;
    int ex0 = base2, ex1 = base2 + a0;
    int n0 = node0 + 2 * tid, n1 = n0 + 1;
    if (n0 < NN) { rowstart[n0] = es + ex0; dinv[n0] = rsqrtf((float)(a0 + 1)); }
    if (n1 < NN) { rowstart[n1] = es + ex1; dinv[n1] = rsqrtf((float)(a1 + 1)); }
    lcur[2 * tid] = es + ex0;
    lcur[2 * tid + 1] = es + ex1;
    __syncthreads();
    for (int i = es + tid; i < ee; i += 256) {
        int e = ebuf[i];
        int pos = atomicAdd(&lcur[e & (BSZ - 1)], 1);
        csr[pos] = ((unsigned)e) >> BSHIFT;
    }
    if (b == 0 && tid == 0) rowstart[NN] = E;
}

// ---------------- W1 -> bf16 transposed [64][512] ----------------
__global__ __launch_bounds__(256) void w1cvt_k(const float* __restrict__ W1,
                                               ushort* __restrict__ w1t) {
    int i = blockIdx.x * 256 + threadIdx.x;
    if (i < FIN * H1D) {
        int n = i >> 9, k = i & 511;
        w1t[i] = f2bf(W1[k * H1D + n]);
    }
}

// ---------------- GEMM1 (MFMA bf16): t1 = bf16( (x @ W1) * dinv ) ----------------
// block = 256 (4 waves), each wave 16 rows x 64 cols, K=512. W1t staged in LDS.
#define BPAD 520
__global__ __launch_bounds__(256) void gemm1_k(const float* __restrict__ x,
                                               const ushort* __restrict__ w1t,
                                               const float* __restrict__ dinv,
                                               ushort* __restrict__ t1) {
    __shared__ ushort sB[H1D * BPAD];   // 66.5 KB, row pad -> 2-way max conflicts
    int tid = threadIdx.x;
    {
        int row = tid >> 2, seg = tid & 3;
        const uint4* srcp = (const uint4*)(w1t + row * FIN + seg * 128);
        uint4* dstp = (uint4*)(sB + row * BPAD + seg * 128);
#pragma unroll
        for (int j = 0; j < 16; ++j) dstp[j] = srcp[j];
    }
    __syncthreads();
    int wave = tid >> 6, lane = tid & 63;
    int lm = lane & 15, q = lane >> 4;
    int r0 = blockIdx.x * 64 + wave * 16;
    int mrow = r0 + lm;
    int mc = mrow < NN ? mrow : NN - 1;
    const float* ap = x + (size_t)mc * FIN + q * 8;
    const ushort* bp = sB + (size_t)lm * BPAD + q * 8;
    f32x4 acc0 = {0.f, 0.f, 0.f, 0.f}, acc1 = acc0, acc2 = acc0, acc3 = acc0;
#pragma unroll 4
    for (int kb = 0; kb < FIN; kb += 32) {
        float4 a01 = *(const float4*)(ap + kb);
        float4 a23 = *(const float4*)(ap + kb + 4);
        union { bf16x8 v8; __hip_bfloat162 h2[4]; } ua;
        ua.h2[0] = __float22bfloat162_rn(make_float2(a01.x, a01.y));
        ua.h2[1] = __float22bfloat162_rn(make_float2(a01.z, a01.w));
        ua.h2[2] = __float22bfloat162_rn(make_float2(a23.x, a23.y));
        ua.h2[3] = __float22bfloat162_rn(make_float2(a23.z, a23.w));
        bf16x8 b0 = *(const bf16x8*)(bp + kb);
        bf16x8 b1 = *(const bf16x8*)(bp + 16 * BPAD + kb);
        bf16x8 b2 = *(const bf16x8*)(bp + 32 * BPAD + kb);
        bf16x8 b3 = *(const bf16x8*)(bp + 48 * BPAD + kb);
        acc0 = __builtin_amdgcn_mfma_f32_16x16x32_bf16(ua.v8, b0, acc0, 0, 0, 0);
        acc1 = __builtin_amdgcn_mfma_f32_16x16x32_bf16(ua.v8, b1, acc1, 0, 0, 0);
        acc2 = __builtin_amdgcn_mfma_f32_16x16x32_bf16(ua.v8, b2, acc2, 0, 0, 0);
        acc3 = __builtin_amdgcn_mfma_f32_16x16x32_bf16(ua.v8, b3, acc3, 0, 0, 0);
    }
    // C/D: col = lane&15 (within 16-col block), row = q*4 + reg
    int rbase = r0 + q * 4;
#pragma unroll
    for (int r = 0; r < 4; ++r) {
        int row = rbase + r;
        if (row < NN) {
            float dv = dinv[row];
            ushort* o = t1 + (size_t)row * H1D;
            o[lm]      = f2bf(acc0[r] * dv);
            o[16 + lm] = f2bf(acc1[r] * dv);
            o[32 + lm] = f2bf(acc2[r] * dv);
            o[48 + lm] = f2bf(acc3[r] * dv);
        }
    }
}

// ---------------- aggregation over 64-dim bf16 rows, one wave per node ----------------
// Lane layout: gsl = lane>>3 (edge slot 0..7), c = lane&7 (uint4 slot: feats 8c..8c+7).
// One gather instr = 8 edges x 16B/lane = 1KB. Explicit 4-batch (32-edge) pipeline.
// Reduce across edge slots via shfl_xor(8,16,32).
// MODE 1: out = relu((dinv*sum)*sc + sv) * dinv     MODE 2: out = dinv*sum
template <int MODE>
__global__ __launch_bounds__(256) void agg64_k(const ushort* __restrict__ tin,
                                               ushort* __restrict__ tout,
                                               const int* __restrict__ rowstart,
                                               const int* __restrict__ csr,
                                               const float* __restrict__ dinv,
                                               const float* __restrict__ g,
                                               const float* __restrict__ bt,
                                               const float* __restrict__ rm,
                                               const float* __restrict__ rv,
                                               const float* __restrict__ b) {
    int wid = (blockIdx.x * blockDim.x + threadIdx.x) >> 6;
    int lane = threadIdx.x & 63;
    if (wid >= NN) return;
    int gsl = lane >> 3;     // edge slot
    int c   = lane & 7;      // feature chunk: feats 8c..8c+7
    int rs = rowstart[wid], re = rowstart[wid + 1];
    float a[8];
#pragma unroll
    for (int j = 0; j < 8; ++j) a[j] = 0.f;
    int i = rs;
    for (; i + 32 <= re; i += 32) {
        int s0 = csr[i + gsl];
        int s1 = csr[i + 8 + gsl];
        int s2 = csr[i + 16 + gsl];
        int s3 = csr[i + 24 + gsl];
        uint4 v0 = *(const uint4*)(tin + (size_t)s0 * H1D + 8 * c);
        uint4 v1 = *(const uint4*)(tin + (size_t)s1 * H1D + 8 * c);
        uint4 v2 = *(const uint4*)(tin + (size_t)s2 * H1D + 8 * c);
        uint4 v3 = *(const uint4*)(tin + (size_t)s3 * H1D + 8 * c);
        acc8(a, v0); acc8(a, v1); acc8(a, v2); acc8(a, v3);
    }
    for (; i + 8 <= re; i += 8) {
        int s0 = csr[i + gsl];
        uint4 v0 = *(const uint4*)(tin + (size_t)s0 * H1D + 8 * c);
        acc8(a, v0);
    }
    if (i + gsl < re) {
        int s0 = csr[i + gsl];
        uint4 v0 = *(const uint4*)(tin + (size_t)s0 * H1D + 8 * c);
        acc8(a, v0);
    }
    // reduce across the 8 edge slots (bits 3..5 of lane)
#pragma unroll
    for (int j = 0; j < 8; ++j) a[j] += __shfl_xor(a[j], 8);
#pragma unroll
    for (int j = 0; j < 8; ++j) a[j] += __shfl_xor(a[j], 16);
#pragma unroll
    for (int j = 0; j < 8; ++j) a[j] += __shfl_xor(a[j], 32);
    // self loop (once per lane, after reduce)
    {
        uint4 sv = *(const uint4*)(tin + (size_t)wid * H1D + 8 * c);
        acc8(a, sv);
    }
    float dv = dinv[wid];
    float z[8];
    if (MODE == 1) {
        int f0 = 8 * c;
        float4 G0 = *(const float4*)(g + f0),  G1 = *(const float4*)(g + f0 + 4);
        float4 V0 = *(const float4*)(rv + f0), V1 = *(const float4*)(rv + f0 + 4);
        float4 B0 = *(const float4*)(b + f0),  B1 = *(const float4*)(b + f0 + 4);
        float4 M0 = *(const float4*)(rm + f0), M1 = *(const float4*)(rm + f0 + 4);
        float4 T0 = *(const float4*)(bt + f0), T1 = *(const float4*)(bt + f0 + 4);
        float sc[8] = { G0.x * rsqrtf(V0.x + BNEPS), G0.y * rsqrtf(V0.y + BNEPS),
                        G0.z * rsqrtf(V0.z + BNEPS), G0.w * rsqrtf(V0.w + BNEPS),
                        G1.x * rsqrtf(V1.x + BNEPS), G1.y * rsqrtf(V1.y + BNEPS),
                        G1.z * rsqrtf(V1.z + BNEPS), G1.w * rsqrtf(V1.w + BNEPS) };
        float sh[8] = { (B0.x - M0.x) * sc[0] + T0.x, (B0.y - M0.y) * sc[1] + T0.y,
                        (B0.z - M0.z) * sc[2] + T0.z, (B0.w - M0.w) * sc[3] + T0.w,
                        (B1.x - M1.x) * sc[4] + T1.x, (B1.y - M1.y) * sc[5] + T1.y,
                        (B1.z - M1.z) * sc[6] + T1.z, (B1.w - M1.w) * sc[7] + T1.w };
#pragma unroll
        for (int j = 0; j < 8; ++j)
            z[j] = fmaxf(a[j] * dv * sc[j] + sh[j], 0.f) * dv;
    } else {
#pragma unroll
        for (int j = 0; j < 8; ++j) z[j] = a[j] * dv;
    }
    if (gsl == 0) {
        uint4 o;
        o.x = (uint)f2bf(z[0]) | ((uint)f2bf(z[1]) << 16);
        o.y = (uint)f2bf(z[2]) | ((uint)f2bf(z[3]) << 16);
        o.z = (uint)f2bf(z[4]) | ((uint)f2bf(z[5]) << 16);
        o.w = (uint)f2bf(z[6]) | ((uint)f2bf(z[7]) << 16);
        *(uint4*)(tout + (size_t)wid * H1D + 8 * c) = o;
    }
}

// ---------------- fused GEMM2 + BN2 + ReLU + GEMM3 (bf16 in, bf16 padded out) ----------------
__global__ __launch_bounds__(256) void p2p3_k(const ushort* __restrict__ u2,
                                              const float* __restrict__ W2,
                                              const float* __restrict__ b2,
                                              const float* __restrict__ W3,
                                              const float* __restrict__ g2,
                                              const float* __restrict__ bt2,
                                              const float* __restrict__ rm2,
                                              const float* __restrict__ rv2,
                                              const float* __restrict__ dinv,
                                              ushort* __restrict__ g3) {
    __shared__ float sW2[H1D * H2D];
    __shared__ float sW3[H2D * CD];
    __shared__ float sc2[H2D], sh2[H2D];
    int tid = threadIdx.x;
    for (int i = tid; i < H1D * H2D; i += 256) sW2[i] = W2[i];
    for (int i = tid; i < H2D * CD; i += 256) sW3[i] = W3[i];
    if (tid < H2D) {
        float s = g2[tid] * rsqrtf(rv2[tid] + BNEPS);
        sc2[tid] = s;
        sh2[tid] = (b2[tid] - rm2[tid]) * s + bt2[tid];
    }
    __syncthreads();
    int node = blockIdx.x * 256 + tid;
    if (node >= NN) return;
    float u[H1D];
    const uint4* up = (const uint4*)(u2 + (size_t)node * H1D);
#pragma unroll
    for (int i = 0; i < 8; ++i) {
        uint4 v = up[i];
        u[8 * i + 0] = bf2f((ushort)(v.x & 0xffff)); u[8 * i + 1] = bf2f((ushort)(v.x >> 16));
        u[8 * i + 2] = bf2f((ushort)(v.y & 0xffff)); u[8 * i + 3] = bf2f((ushort)(v.y >> 16));
        u[8 * i + 4] = bf2f((ushort)(v.z & 0xffff)); u[8 * i + 5] = bf2f((ushort)(v.z >> 16));
        u[8 * i + 6] = bf2f((ushort)(v.w & 0xffff)); u[8 * i + 7] = bf2f((ushort)(v.w >> 16));
    }
    float gacc[CD];
#pragma unroll
    for (int c = 0; c < CD; ++c) gacc[c] = 0.f;
    for (int fc = 0; fc < H2D; fc += 32) {
        float a[32];
#pragma unroll
        for (int j = 0; j < 32; ++j) a[j] = 0.f;
        for (int l = 0; l < H1D; ++l) {
            float ul = u[l];
            const float4* wr = (const float4*)&sW2[l * H2D + fc];
#pragma unroll
            for (int j = 0; j < 8; ++j) {
                float4 w = wr[j];
                a[4 * j]     += ul * w.x;
                a[4 * j + 1] += ul * w.y;
                a[4 * j + 2] += ul * w.z;
                a[4 * j + 3] += ul * w.w;
            }
        }
#pragma unroll
        for (int j = 0; j < 32; ++j) {
            int f = fc + j;
            float hv = fmaxf(a[j] * sc2[f] + sh2[f], 0.f);
            const float4* w3r = (const float4*)&sW3[f * CD];
#pragma unroll
            for (int c = 0; c < 10; ++c) {
                float4 w = w3r[c];
                gacc[4 * c]     += hv * w.x;
                gacc[4 * c + 1] += hv * w.y;
                gacc[4 * c + 2] += hv * w.z;
                gacc[4 * c + 3] += hv * w.w;
            }
        }
    }
    float dv = dinv[node];
    ushort* op = g3 + (size_t)node * GP;
#pragma unroll
    for (int c = 0; c < 10; ++c) {
        uint pk  = (uint)f2bf(gacc[4 * c] * dv)     | ((uint)f2bf(gacc[4 * c + 1] * dv) << 16);
        uint pk2 = (uint)f2bf(gacc[4 * c + 2] * dv) | ((uint)f2bf(gacc[4 * c + 3] * dv) << 16);
        *(uint2*)&op[4 * c] = make_uint2(pk, pk2);
    }
    // pad cols 40..63 are never read by agg40 (gathers predicated to c<5) -> no zeroing needed
}

// ---------------- aggregation over padded 40-dim bf16 + bias + log_softmax ----------------
// Same 8-edge/instr layout; only uint4 slots c<5 are real (CD=40=5*8), pad never read.
__global__ __launch_bounds__(256) void agg40_k(const ushort* __restrict__ g3,
                                               const float* __restrict__ b3,
                                               const int* __restrict__ rowstart,
                                               const int* __restrict__ csr,
                                               const float* __restrict__ dinv,
                                               float* __restrict__ out) {
    int wid = (blockIdx.x * blockDim.x + threadIdx.x) >> 6;
    int lane = threadIdx.x & 63;
    if (wid >= NN) return;
    int gsl = lane >> 3;
    int c   = lane & 7;
    int rs = rowstart[wid], re = rowstart[wid + 1];
    float a[8];
#pragma unroll
    for (int j = 0; j < 8; ++j) a[j] = 0.f;
    if (c < 5) {
        int i = rs;
        for (; i + 32 <= re; i += 32) {
            int s0 = csr[i + gsl];
            int s1 = csr[i + 8 + gsl];
            int s2 = csr[i + 16 + gsl];
            int s3 = csr[i + 24 + gsl];
            uint4 v0 = *(const uint4*)(g3 + (size_t)s0 * GP + 8 * c);
            uint4 v1 = *(const uint4*)(g3 + (size_t)s1 * GP + 8 * c);
            uint4 v2 = *(const uint4*)(g3 + (size_t)s2 * GP + 8 * c);
            uint4 v3 = *(const uint4*)(g3 + (size_t)s3 * GP + 8 * c);
            acc8(a, v0); acc8(a, v1); acc8(a, v2); acc8(a, v3);
        }
        for (; i + 8 <= re; i += 8) {
            int s0 = csr[i + gsl];
            uint4 v0 = *(const uint4*)(g3 + (size_t)s0 * GP + 8 * c);
            acc8(a, v0);
        }
        if (i + gsl < re) {
            int s0 = csr[i + gsl];
            uint4 v0 = *(const uint4*)(g3 + (size_t)s0 * GP + 8 * c);
            acc8(a, v0);
        }
    }
#pragma unroll
    for (int j = 0; j < 8; ++j) a[j] += __shfl_xor(a[j], 8);
#pragma unroll
    for (int j = 0; j < 8; ++j) a[j] += __shfl_xor(a[j], 16);
#pragma unroll
    for (int j = 0; j < 8; ++j) a[j] += __shfl_xor(a[j], 32);
    if (c < 5) {
        uint4 sv = *(const uint4*)(g3 + (size_t)wid * GP + 8 * c);
        acc8(a, sv);
    }
    float dv = dinv[wid];
    float z[8];
    if (c < 5) {
        int f0 = 8 * c;
        float4 bb0 = *(const float4*)(b3 + f0);
        float4 bb1 = *(const float4*)(b3 + f0 + 4);
        z[0] = a[0] * dv + bb0.x; z[1] = a[1] * dv + bb0.y;
        z[2] = a[2] * dv + bb0.z; z[3] = a[3] * dv + bb0.w;
        z[4] = a[4] * dv + bb1.x; z[5] = a[5] * dv + bb1.y;
        z[6] = a[6] * dv + bb1.z; z[7] = a[7] * dv + bb1.w;
    } else {
#pragma unroll
        for (int j = 0; j < 8; ++j) z[j] = -1e30f;
    }
    float m = fmaxf(fmaxf(fmaxf(z[0], z[1]), fmaxf(z[2], z[3])),
                    fmaxf(fmaxf(z[4], z[5]), fmaxf(z[6], z[7])));
    m = fmaxf(m, __shfl_xor(m, 1));
    m = fmaxf(m, __shfl_xor(m, 2));
    m = fmaxf(m, __shfl_xor(m, 4));
    float e = 0.f;
    if (c < 5) {
#pragma unroll
        for (int j = 0; j < 8; ++j) e += __expf(z[j] - m);
    }
    e += __shfl_xor(e, 1);
    e += __shfl_xor(e, 2);
    e += __shfl_xor(e, 4);
    float ls = __logf(e);
    if (gsl == 0 && c < 5) {
        int f0 = 8 * c;
        float4 o0 = { z[0] - m - ls, z[1] - m - ls, z[2] - m - ls, z[3] - m - ls };
        float4 o1 = { z[4] - m - ls, z[5] - m - ls, z[6] - m - ls, z[7] - m - ls };
        *(float4*)(out + (size_t)wid * CD + f0)     = o0;
        *(float4*)(out + (size_t)wid * CD + f0 + 4) = o1;
    }
}

// ---------------- launcher ----------------

extern "C" void kernel_launch(void* const* d_in, const int* in_sizes, int n_in,
                              void* d_out, int out_size, void* d_ws, size_t ws_size,
                              hipStream_t stream) {
    (void)n_in; (void)out_size; (void)ws_size;
    const float* x   = (const float*)d_in[0];
    const int*   ei  = (const int*)d_in[1];
    const float* W1  = (const float*)d_in[2];
    const float* b1  = (const float*)d_in[3];
    const float* W2  = (const float*)d_in[4];
    const float* b2  = (const float*)d_in[5];
    const float* W3  = (const float*)d_in[6];
    const float* b3  = (const float*)d_in[7];
    const float* g1  = (const float*)d_in[8];
    const float* bt1 = (const float*)d_in[9];
    const float* rm1 = (const float*)d_in[10];
    const float* rv1 = (const float*)d_in[11];
    const float* g2  = (const float*)d_in[12];
    const float* bt2 = (const float*)d_in[13];
    const float* rm2 = (const float*)d_in[14];
    const float* rv2 = (const float*)d_in[15];
    float* out = (float*)d_out;
    const int E = in_sizes[1] / 2;

    char* w = (char*)d_ws;
    auto alloc = [&](size_t bytes) { char* p = w; w += (bytes + 511) & ~(size_t)511; return p; };
    int*    bcount   = (int*)alloc((size_t)NB * 4);
    int*    bstart   = (int*)alloc((size_t)(NB + 1) * 4);
    int*    bcursor  = (int*)alloc((size_t)NB * 4);
    int*    rowstart = (int*)alloc((size_t)(NN + 1) * 4);
    float*  dinv     = (float*)alloc((size_t)NN * 4);
    int*    csr      = (int*)alloc((size_t)E * 4);
    int*    ebuf     = (int*)alloc((size_t)E * 4);
    ushort* w1t      = (ushort*)alloc((size_t)H1D * FIN * 2);
    ushort* t1       = (ushort*)alloc((size_t)NN * H1D * 2);  // reused as u2
    ushort* t2       = (ushort*)alloc((size_t)NN * H1D * 2);
    ushort* g3       = (ushort*)alloc((size_t)NN * GP * 2);

    hipMemsetAsync(bcount, 0, (size_t)NB * 4, stream);
    bhist_k<<<512, 256, 0, stream>>>(ei + E, E, bcount);
    bscan_k<<<1, 256, 0, stream>>>(bcount, bstart, bcursor);
    bscatter_k<<<(E + CHUNK - 1) / CHUNK, 256, 0, stream>>>(ei, ei + E, E, bcursor, ebuf);
    bcsr_k<<<NB, 256, 0, stream>>>(ebuf, bstart, rowstart, dinv, csr, E);
    w1cvt_k<<<(FIN * H1D + 255) / 256, 256, 0, stream>>>(W1, w1t);
    gemm1_k<<<(NN + 63) / 64, 256, 0, stream>>>(x, w1t, dinv, t1);
    agg64_k<1><<<(NN + 3) / 4, 256, 0, stream>>>(t1, t2, rowstart, csr, dinv, g1, bt1, rm1, rv1, b1);
    agg64_k<2><<<(NN + 3) / 4, 256, 0, stream>>>(t2, t1, rowstart, csr, dinv, nullptr, nullptr, nullptr, nullptr, nullptr);
    p2p3_k<<<(NN + 255) / 256, 256, 0, stream>>>(t1, W2, b2, W3, g2, bt2, rm2, rv2, dinv, g3);
    agg40_k<<<(NN + 3) / 4, 256, 0, stream>>>(g3, b3, rowstart, csr, dinv, out);
}

// Round 2
// 713.989 us; speedup vs baseline: 1.1933x; 1.0289x over previous
//
#include <hip/hip_runtime.h>
#include <hip/hip_bf16.h>

#define NN 100000
#define FIN 512
#define H1D 64
#define H2D 128
#define CD 40
#define GP 64           // g3 padded row (bf16) -> one 128B line
#define BNEPS 1e-5f

#define BSHIFT 9
#define BSZ 512
#define NB 196          // ceil(NN / 512)
#define CHUNK 8192      // edges per scatter block

typedef __attribute__((ext_vector_type(8))) short bf16x8;
typedef __attribute__((ext_vector_type(4))) float f32x4;

__device__ __forceinline__ float bf2f(ushort u) {
    union { uint i; float f; } v; v.i = ((uint)u) << 16; return v.f;
}
__device__ __forceinline__ ushort f2bf(float f) {
    union { float f; uint i; } v; v.f = f;
    uint x = v.i;
    return (ushort)((x + 0x7fffu + ((x >> 16) & 1u)) >> 16);
}

// unpack 8 bf16 (one 16B row chunk) and accumulate into a[0..7]
__device__ __forceinline__ void acc8(float* a, uint4 v) {
    a[0] += bf2f((ushort)(v.x & 0xffff)); a[1] += bf2f((ushort)(v.x >> 16));
    a[2] += bf2f((ushort)(v.y & 0xffff)); a[3] += bf2f((ushort)(v.y >> 16));
    a[4] += bf2f((ushort)(v.z & 0xffff)); a[5] += bf2f((ushort)(v.z >> 16));
    a[6] += bf2f((ushort)(v.w & 0xffff)); a[7] += bf2f((ushort)(v.w >> 16));
}

__device__ __forceinline__ uint4 selz(bool q, uint4 v) {
    return q ? v : make_uint4(0u, 0u, 0u, 0u);
}

// ---------------- graph preprocessing: bucketed CSR build ----------------

__global__ __launch_bounds__(256) void bhist_k(const int* __restrict__ dst, int E,
                                               int* __restrict__ bcount) {
    __shared__ int h[NB];
    for (int i = threadIdx.x; i < NB; i += 256) h[i] = 0;
    __syncthreads();
    int i = blockIdx.x * blockDim.x + threadIdx.x;
    int st = gridDim.x * blockDim.x;
    for (; i < E; i += st) atomicAdd(&h[dst[i] >> BSHIFT], 1);
    __syncthreads();
    for (int j = threadIdx.x; j < NB; j += 256)
        if (h[j]) atomicAdd(&bcount[j], h[j]);
}

__global__ __launch_bounds__(256) void bscan_k(const int* __restrict__ bcount,
                                               int* __restrict__ bstart,
                                               int* __restrict__ bcursor) {
    __shared__ int sh[NB];
    int tid = threadIdx.x;
    if (tid < NB) sh[tid] = bcount[tid];
    __syncthreads();
    for (int off = 1; off < NB; off <<= 1) {
        int v = (tid < NB && tid >= off) ? sh[tid - off] : 0;
        __syncthreads();
        if (tid < NB) sh[tid] += v;
        __syncthreads();
    }
    if (tid < NB) {
        int s = tid ? sh[tid - 1] : 0;
        bstart[tid] = s;
        bcursor[tid] = s;
    }
    if (tid == 0) bstart[NB] = sh[NB - 1];
}

__global__ __launch_bounds__(256) void bscatter_k(const int* __restrict__ src,
                                                  const int* __restrict__ dst, int E,
                                                  int* __restrict__ bcursor,
                                                  int* __restrict__ ebuf) {
    __shared__ int hist[NB];
    __shared__ int loff[NB];
    __shared__ int lcur[NB];
    __shared__ int gbase[NB];
    __shared__ int sbuf[CHUNK];
    int tid = threadIdx.x;
    int e0 = blockIdx.x * CHUNK;
    int e1 = e0 + CHUNK; if (e1 > E) e1 = E;

    for (int i = tid; i < NB; i += 256) hist[i] = 0;
    __syncthreads();
    for (int i = e0 + tid; i < e1; i += 256) atomicAdd(&hist[dst[i] >> BSHIFT], 1);
    __syncthreads();
    int v = (tid < NB) ? hist[tid] : 0;
    __syncthreads();
    if (tid < NB) loff[tid] = v;
    __syncthreads();
    for (int off = 1; off < NB; off <<= 1) {
        int u = (tid < NB && tid >= off) ? loff[tid - off] : 0;
        __syncthreads();
        if (tid < NB) loff[tid] += u;
        __syncthreads();
    }
    if (tid < NB) {
        int excl = loff[tid] - v;
        loff[tid] = excl;
        lcur[tid] = excl;
        gbase[tid] = (v > 0) ? atomicAdd(&bcursor[tid], v) : 0;
    }
    __syncthreads();
    for (int i = e0 + tid; i < e1; i += 256) {
        int d = dst[i];
        int b = d >> BSHIFT;
        int pos = atomicAdd(&lcur[b], 1);
        sbuf[pos] = (src[i] << BSHIFT) | (d & (BSZ - 1));
    }
    __syncthreads();
    int wave = tid >> 6, lane = tid & 63;
    for (int b = wave; b < NB; b += 4) {
        int cnt = (b + 1 < NB ? loff[b + 1] : (e1 - e0)) - loff[b];
        int s0 = loff[b], d0 = gbase[b];
        for (int k = lane; k < cnt; k += 64) ebuf[d0 + k] = sbuf[s0 + k];
    }
}

__global__ __launch_bounds__(256) void bcsr_k(const int* __restrict__ ebuf,
                                              const int* __restrict__ bstart,
                                              int* __restrict__ rowstart,
                                              float* __restrict__ dinv,
                                              int* __restrict__ csr, int E) {
    __shared__ int ldeg[BSZ];
    __shared__ int lcur[BSZ];
    __shared__ int s2[256];
    int b = blockIdx.x, tid = threadIdx.x;
    int node0 = b << BSHIFT;
    int es = bstart[b], ee = bstart[b + 1];
    ldeg[tid] = 0; ldeg[tid + 256] = 0;
    __syncthreads();
    for (int i = es + tid; i < ee; i += 256) atomicAdd(&ldeg[ebuf[i] & (BSZ - 1)], 1);
    __syncthreads();
    int a0 = ldeg[2 * tid], a1 = ldeg[2 * tid + 1];
    s2[tid] = a0 + a1;
    __syncthreads();
    for (int off = 1; off < 256; off <<= 1) {
        int u = (tid >= off) ? s2[tid - off] : 0;
        __syncthreads();
        s2[tid] += u;
        __syncthreads();
    }
    int base2 = tid ? s2[tid - 1] : 0;
    int ex0 = base2, ex1 = base2 + a0;
    int n0 = node0 + 2 * tid, n1 = n0 + 1;
    if (n0 < NN) { rowstart[n0] = es + ex0; dinv[n0] = rsqrtf((float)(a0 + 1)); }
    if (n1 < NN) { rowstart[n1] = es + ex1; dinv[n1] = rsqrtf((float)(a1 + 1)); }
    lcur[2 * tid] = es + ex0;
    lcur[2 * tid + 1] = es + ex1;
    __syncthreads();
    for (int i = es + tid; i < ee; i += 256) {
        int e = ebuf[i];
        int pos = atomicAdd(&lcur[e & (BSZ - 1)], 1);
        csr[pos] = ((unsigned)e) >> BSHIFT;
    }
    if (b == 0 && tid == 0) rowstart[NN] = E;
}

// ---------------- W1 -> bf16 transposed [64][512] ----------------
__global__ __launch_bounds__(256) void w1cvt_k(const float* __restrict__ W1,
                                               ushort* __restrict__ w1t) {
    int i = blockIdx.x * 256 + threadIdx.x;
    if (i < FIN * H1D) {
        int n = i >> 9, k = i & 511;
        w1t[i] = f2bf(W1[k * H1D + n]);
    }
}

// ---------------- GEMM1 (MFMA bf16): t1 = bf16( (x @ W1) * dinv ) ----------------
// block = 256 (4 waves), each wave 16 rows x 64 cols, K=512. W1t staged in LDS.
#define BPAD 520
__global__ __launch_bounds__(256) void gemm1_k(const float* __restrict__ x,
                                               const ushort* __restrict__ w1t,
                                               const float* __restrict__ dinv,
                                               ushort* __restrict__ t1) {
    __shared__ ushort sB[H1D * BPAD];   // 66.5 KB, row pad -> 2-way max conflicts
    int tid = threadIdx.x;
    {
        int row = tid >> 2, seg = tid & 3;
        const uint4* srcp = (const uint4*)(w1t + row * FIN + seg * 128);
        uint4* dstp = (uint4*)(sB + row * BPAD + seg * 128);
#pragma unroll
        for (int j = 0; j < 16; ++j) dstp[j] = srcp[j];
    }
    __syncthreads();
    int wave = tid >> 6, lane = tid & 63;
    int lm = lane & 15, q = lane >> 4;
    int r0 = blockIdx.x * 64 + wave * 16;
    int mrow = r0 + lm;
    int mc = mrow < NN ? mrow : NN - 1;
    const float* ap = x + (size_t)mc * FIN + q * 8;
    const ushort* bp = sB + (size_t)lm * BPAD + q * 8;
    f32x4 acc0 = {0.f, 0.f, 0.f, 0.f}, acc1 = acc0, acc2 = acc0, acc3 = acc0;
#pragma unroll 4
    for (int kb = 0; kb < FIN; kb += 32) {
        f32x4 a01 = __builtin_nontemporal_load((const f32x4*)(ap + kb));
        f32x4 a23 = __builtin_nontemporal_load((const f32x4*)(ap + kb + 4));
        union { bf16x8 v8; __hip_bfloat162 h2[4]; } ua;
        ua.h2[0] = __float22bfloat162_rn(make_float2(a01[0], a01[1]));
        ua.h2[1] = __float22bfloat162_rn(make_float2(a01[2], a01[3]));
        ua.h2[2] = __float22bfloat162_rn(make_float2(a23[0], a23[1]));
        ua.h2[3] = __float22bfloat162_rn(make_float2(a23[2], a23[3]));
        bf16x8 b0 = *(const bf16x8*)(bp + kb);
        bf16x8 b1 = *(const bf16x8*)(bp + 16 * BPAD + kb);
        bf16x8 b2 = *(const bf16x8*)(bp + 32 * BPAD + kb);
        bf16x8 b3 = *(const bf16x8*)(bp + 48 * BPAD + kb);
        acc0 = __builtin_amdgcn_mfma_f32_16x16x32_bf16(ua.v8, b0, acc0, 0, 0, 0);
        acc1 = __builtin_amdgcn_mfma_f32_16x16x32_bf16(ua.v8, b1, acc1, 0, 0, 0);
        acc2 = __builtin_amdgcn_mfma_f32_16x16x32_bf16(ua.v8, b2, acc2, 0, 0, 0);
        acc3 = __builtin_amdgcn_mfma_f32_16x16x32_bf16(ua.v8, b3, acc3, 0, 0, 0);
    }
    // C/D: col = lane&15 (within 16-col block), row = q*4 + reg
    int rbase = r0 + q * 4;
#pragma unroll
    for (int r = 0; r < 4; ++r) {
        int row = rbase + r;
        if (row < NN) {
            float dv = dinv[row];
            ushort* o = t1 + (size_t)row * H1D;
            o[lm]      = f2bf(acc0[r] * dv);
            o[16 + lm] = f2bf(acc1[r] * dv);
            o[32 + lm] = f2bf(acc2[r] * dv);
            o[48 + lm] = f2bf(acc3[r] * dv);
        }
    }
}

// ---------------- aggregation over 64-dim bf16 rows, TWO nodes per wave ----------------
// Lane layout: gsl = lane>>3 (edge slot 0..7), c = lane&7 (uint4 slot: feats 8c..8c+7).
// One gather instr = 8 edges x 16B/lane = 1KB. Two independent chains (nodes A,B)
// per wave -> 8 gathers in flight. Remainder handled by ONE masked batch
// (sink-clamped indices -> single hot line, cndmask zeroing, no divergence).
// MODE 1: out = relu((dinv*sum)*sc + sv) * dinv     MODE 2: out = dinv*sum
template <int MODE>
__global__ __launch_bounds__(256) void agg64_k(const ushort* __restrict__ tin,
                                               ushort* __restrict__ tout,
                                               const int* __restrict__ rowstart,
                                               const int* __restrict__ csr,
                                               const float* __restrict__ dinv,
                                               const float* __restrict__ g,
                                               const float* __restrict__ bt,
                                               const float* __restrict__ rm,
                                               const float* __restrict__ rv,
                                               const float* __restrict__ b,
                                               int E) {
    int w = (blockIdx.x * blockDim.x + threadIdx.x) >> 6;
    int lane = threadIdx.x & 63;
    int nA = 2 * w;
    if (nA >= NN) return;
    int nB = nA + 1;                 // NN even -> always valid
    int gsl = lane >> 3, c = lane & 7;
    int base = 8 * c;
    int2 r01 = *(const int2*)(rowstart + nA);
    int reB = rowstart[nA + 2];
    int iA = r01.x, reA = r01.y;
    int iB = reA;
    int Em1 = E - 1;
    float a[8], y[8];
#pragma unroll
    for (int j = 0; j < 8; ++j) { a[j] = 0.f; y[j] = 0.f; }

    for (;;) {
        bool dA = (iA + 32 <= reA);
        bool dB = (iB + 32 <= reB);
        if (!(dA | dB)) break;
        int jA0 = dA ? iA + gsl      : Em1;
        int jA1 = dA ? iA + 8 + gsl  : Em1;
        int jA2 = dA ? iA + 16 + gsl : Em1;
        int jA3 = dA ? iA + 24 + gsl : Em1;
        int jB0 = dB ? iB + gsl      : Em1;
        int jB1 = dB ? iB + 8 + gsl  : Em1;
        int jB2 = dB ? iB + 16 + gsl : Em1;
        int jB3 = dB ? iB + 24 + gsl : Em1;
        int sA0 = csr[jA0], sA1 = csr[jA1], sA2 = csr[jA2], sA3 = csr[jA3];
        int sB0 = csr[jB0], sB1 = csr[jB1], sB2 = csr[jB2], sB3 = csr[jB3];
        uint4 vA0 = *(const uint4*)(tin + (size_t)sA0 * H1D + base);
        uint4 vA1 = *(const uint4*)(tin + (size_t)sA1 * H1D + base);
        uint4 vA2 = *(const uint4*)(tin + (size_t)sA2 * H1D + base);
        uint4 vA3 = *(const uint4*)(tin + (size_t)sA3 * H1D + base);
        uint4 vB0 = *(const uint4*)(tin + (size_t)sB0 * H1D + base);
        uint4 vB1 = *(const uint4*)(tin + (size_t)sB1 * H1D + base);
        uint4 vB2 = *(const uint4*)(tin + (size_t)sB2 * H1D + base);
        uint4 vB3 = *(const uint4*)(tin + (size_t)sB3 * H1D + base);
        vA0 = selz(dA, vA0); vA1 = selz(dA, vA1); vA2 = selz(dA, vA2); vA3 = selz(dA, vA3);
        vB0 = selz(dB, vB0); vB1 = selz(dB, vB1); vB2 = selz(dB, vB2); vB3 = selz(dB, vB3);
        acc8(a, vA0); acc8(a, vA1); acc8(a, vA2); acc8(a, vA3);
        acc8(y, vB0); acc8(y, vB1); acc8(y, vB2); acc8(y, vB3);
        iA += dA ? 32 : 0;
        iB += dB ? 32 : 0;
    }
    // masked remainder batch (<=31 edges per node), 8 gathers in flight
    {
        bool qA0 = iA + gsl < reA,      qB0 = iB + gsl < reB;
        bool qA1 = iA + 8 + gsl < reA,  qB1 = iB + 8 + gsl < reB;
        bool qA2 = iA + 16 + gsl < reA, qB2 = iB + 16 + gsl < reB;
        bool qA3 = iA + 24 + gsl < reA, qB3 = iB + 24 + gsl < reB;
        int jA0 = qA0 ? iA + gsl      : Em1;
        int jA1 = qA1 ? iA + 8 + gsl  : Em1;
        int jA2 = qA2 ? iA + 16 + gsl : Em1;
        int jA3 = qA3 ? iA + 24 + gsl : Em1;
        int jB0 = qB0 ? iB + gsl      : Em1;
        int jB1 = qB1 ? iB + 8 + gsl  : Em1;
        int jB2 = qB2 ? iB + 16 + gsl : Em1;
        int jB3 = qB3 ? iB + 24 + gsl : Em1;
        int sA0 = csr[jA0], sA1 = csr[jA1], sA2 = csr[jA2], sA3 = csr[jA3];
        int sB0 = csr[jB0], sB1 = csr[jB1], sB2 = csr[jB2], sB3 = csr[jB3];
        uint4 vA0 = *(const uint4*)(tin + (size_t)sA0 * H1D + base);
        uint4 vA1 = *(const uint4*)(tin + (size_t)sA1 * H1D + base);
        uint4 vA2 = *(const uint4*)(tin + (size_t)sA2 * H1D + base);
        uint4 vA3 = *(const uint4*)(tin + (size_t)sA3 * H1D + base);
        uint4 vB0 = *(const uint4*)(tin + (size_t)sB0 * H1D + base);
        uint4 vB1 = *(const uint4*)(tin + (size_t)sB1 * H1D + base);
        uint4 vB2 = *(const uint4*)(tin + (size_t)sB2 * H1D + base);
        uint4 vB3 = *(const uint4*)(tin + (size_t)sB3 * H1D + base);
        vA0 = selz(qA0, vA0); vA1 = selz(qA1, vA1); vA2 = selz(qA2, vA2); vA3 = selz(qA3, vA3);
        vB0 = selz(qB0, vB0); vB1 = selz(qB1, vB1); vB2 = selz(qB2, vB2); vB3 = selz(qB3, vB3);
        acc8(a, vA0); acc8(a, vA1); acc8(a, vA2); acc8(a, vA3);
        acc8(y, vB0); acc8(y, vB1); acc8(y, vB2); acc8(y, vB3);
    }
    // self rows (issue loads before the shfl chain; accumulate after reduce)
    uint4 svA = *(const uint4*)(tin + (size_t)nA * H1D + base);
    uint4 svB = *(const uint4*)(tin + (size_t)nB * H1D + base);
    // reduce across the 8 edge slots (bits 3..5 of lane)
#pragma unroll
    for (int j = 0; j < 8; ++j) a[j] += __shfl_xor(a[j], 8);
#pragma unroll
    for (int j = 0; j < 8; ++j) a[j] += __shfl_xor(a[j], 16);
#pragma unroll
    for (int j = 0; j < 8; ++j) a[j] += __shfl_xor(a[j], 32);
#pragma unroll
    for (int j = 0; j < 8; ++j) y[j] += __shfl_xor(y[j], 8);
#pragma unroll
    for (int j = 0; j < 8; ++j) y[j] += __shfl_xor(y[j], 16);
#pragma unroll
    for (int j = 0; j < 8; ++j) y[j] += __shfl_xor(y[j], 32);
    acc8(a, svA);
    acc8(y, svB);
    // lane-select: gsl==0 lanes carry node A, gsl==1 lanes carry node B
    float2 dv2 = *(const float2*)(dinv + nA);
    float dv = (gsl == 0) ? dv2.x : dv2.y;
    float s[8];
#pragma unroll
    for (int j = 0; j < 8; ++j) s[j] = (gsl == 0) ? a[j] : y[j];
    float z[8];
    if (MODE == 1) {
        int f0 = base;
        float4 G0 = *(const float4*)(g + f0),  G1 = *(const float4*)(g + f0 + 4);
        float4 V0 = *(const float4*)(rv + f0), V1 = *(const float4*)(rv + f0 + 4);
        float4 B0 = *(const float4*)(b + f0),  B1 = *(const float4*)(b + f0 + 4);
        float4 M0 = *(const float4*)(rm + f0), M1 = *(const float4*)(rm + f0 + 4);
        float4 T0 = *(const float4*)(bt + f0), T1 = *(const float4*)(bt + f0 + 4);
        float sc[8] = { G0.x * rsqrtf(V0.x + BNEPS), G0.y * rsqrtf(V0.y + BNEPS),
                        G0.z * rsqrtf(V0.z + BNEPS), G0.w * rsqrtf(V0.w + BNEPS),
                        G1.x * rsqrtf(V1.x + BNEPS), G1.y * rsqrtf(V1.y + BNEPS),
                        G1.z * rsqrtf(V1.z + BNEPS), G1.w * rsqrtf(V1.w + BNEPS) };
        float sh[8] = { (B0.x - M0.x) * sc[0] + T0.x, (B0.y - M0.y) * sc[1] + T0.y,
                        (B0.z - M0.z) * sc[2] + T0.z, (B0.w - M0.w) * sc[3] + T0.w,
                        (B1.x - M1.x) * sc[4] + T1.x, (B1.y - M1.y) * sc[5] + T1.y,
                        (B1.z - M1.z) * sc[6] + T1.z, (B1.w - M1.w) * sc[7] + T1.w };
#pragma unroll
        for (int j = 0; j < 8; ++j)
            z[j] = fmaxf(s[j] * dv * sc[j] + sh[j], 0.f) * dv;
    } else {
#pragma unroll
        for (int j = 0; j < 8; ++j) z[j] = s[j] * dv;
    }
    if (gsl < 2) {
        uint4 o;
        o.x = (uint)f2bf(z[0]) | ((uint)f2bf(z[1]) << 16);
        o.y = (uint)f2bf(z[2]) | ((uint)f2bf(z[3]) << 16);
        o.z = (uint)f2bf(z[4]) | ((uint)f2bf(z[5]) << 16);
        o.w = (uint)f2bf(z[6]) | ((uint)f2bf(z[7]) << 16);
        *(uint4*)(tout + (size_t)(nA + gsl) * H1D + base) = o;
    }
}

// ---------------- fused GEMM2 + BN2 + ReLU + GEMM3 (bf16 in, bf16 padded out) ----------------
__global__ __launch_bounds__(256) void p2p3_k(const ushort* __restrict__ u2,
                                              const float* __restrict__ W2,
                                              const float* __restrict__ b2,
                                              const float* __restrict__ W3,
                                              const float* __restrict__ g2,
                                              const float* __restrict__ bt2,
                                              const float* __restrict__ rm2,
                                              const float* __restrict__ rv2,
                                              const float* __restrict__ dinv,
                                              ushort* __restrict__ g3) {
    __shared__ float sW2[H1D * H2D];
    __shared__ float sW3[H2D * CD];
    __shared__ float sc2[H2D], sh2[H2D];
    int tid = threadIdx.x;
    for (int i = tid; i < H1D * H2D; i += 256) sW2[i] = W2[i];
    for (int i = tid; i < H2D * CD; i += 256) sW3[i] = W3[i];
    if (tid < H2D) {
        float s = g2[tid] * rsqrtf(rv2[tid] + BNEPS);
        sc2[tid] = s;
        sh2[tid] = (b2[tid] - rm2[tid]) * s + bt2[tid];
    }
    __syncthreads();
    int node = blockIdx.x * 256 + tid;
    if (node >= NN) return;
    float u[H1D];
    const uint4* up = (const uint4*)(u2 + (size_t)node * H1D);
#pragma unroll
    for (int i = 0; i < 8; ++i) {
        uint4 v = up[i];
        u[8 * i + 0] = bf2f((ushort)(v.x & 0xffff)); u[8 * i + 1] = bf2f((ushort)(v.x >> 16));
        u[8 * i + 2] = bf2f((ushort)(v.y & 0xffff)); u[8 * i + 3] = bf2f((ushort)(v.y >> 16));
        u[8 * i + 4] = bf2f((ushort)(v.z & 0xffff)); u[8 * i + 5] = bf2f((ushort)(v.z >> 16));
        u[8 * i + 6] = bf2f((ushort)(v.w & 0xffff)); u[8 * i + 7] = bf2f((ushort)(v.w >> 16));
    }
    float gacc[CD];
#pragma unroll
    for (int c = 0; c < CD; ++c) gacc[c] = 0.f;
    for (int fc = 0; fc < H2D; fc += 32) {
        float a[32];
#pragma unroll
        for (int j = 0; j < 32; ++j) a[j] = 0.f;
        for (int l = 0; l < H1D; ++l) {
            float ul = u[l];
            const float4* wr = (const float4*)&sW2[l * H2D + fc];
#pragma unroll
            for (int j = 0; j < 8; ++j) {
                float4 w = wr[j];
                a[4 * j]     += ul * w.x;
                a[4 * j + 1] += ul * w.y;
                a[4 * j + 2] += ul * w.z;
                a[4 * j + 3] += ul * w.w;
            }
        }
#pragma unroll
        for (int j = 0; j < 32; ++j) {
            int f = fc + j;
            float hv = fmaxf(a[j] * sc2[f] + sh2[f], 0.f);
            const float4* w3r = (const float4*)&sW3[f * CD];
#pragma unroll
            for (int c = 0; c < 10; ++c) {
                float4 w = w3r[c];
                gacc[4 * c]     += hv * w.x;
                gacc[4 * c + 1] += hv * w.y;
                gacc[4 * c + 2] += hv * w.z;
                gacc[4 * c + 3] += hv * w.w;
            }
        }
    }
    float dv = dinv[node];
    ushort* op = g3 + (size_t)node * GP;
#pragma unroll
    for (int c = 0; c < 10; ++c) {
        uint pk  = (uint)f2bf(gacc[4 * c] * dv)     | ((uint)f2bf(gacc[4 * c + 1] * dv) << 16);
        uint pk2 = (uint)f2bf(gacc[4 * c + 2] * dv) | ((uint)f2bf(gacc[4 * c + 3] * dv) << 16);
        *(uint2*)&op[4 * c] = make_uint2(pk, pk2);
    }
    // pad cols 40..63: agg40 may READ them (uniform gathers) but never uses the
    // values numerically (z for c>=5 is forced to -1e30 / excluded) -> no zeroing.
}

// ---------------- aggregation over padded 40-dim bf16 + bias + log_softmax ----------------
// Same 2-node/8-gather structure as agg64. Lanes c>=5 gather pad bytes (same 128B
// line, no extra traffic); their values are never used numerically.
__global__ __launch_bounds__(256) void agg40_k(const ushort* __restrict__ g3,
                                               const float* __restrict__ b3,
                                               const int* __restrict__ rowstart,
                                               const int* __restrict__ csr,
                                               const float* __restrict__ dinv,
                                               float* __restrict__ out,
                                               int E) {
    int w = (blockIdx.x * blockDim.x + threadIdx.x) >> 6;
    int lane = threadIdx.x & 63;
    int nA = 2 * w;
    if (nA >= NN) return;
    int nB = nA + 1;
    int gsl = lane >> 3, c = lane & 7;
    int base = 8 * c;
    int2 r01 = *(const int2*)(rowstart + nA);
    int reB = rowstart[nA + 2];
    int iA = r01.x, reA = r01.y;
    int iB = reA;
    int Em1 = E - 1;
    float a[8], y[8];
#pragma unroll
    for (int j = 0; j < 8; ++j) { a[j] = 0.f; y[j] = 0.f; }

    for (;;) {
        bool dA = (iA + 32 <= reA);
        bool dB = (iB + 32 <= reB);
        if (!(dA | dB)) break;
        int jA0 = dA ? iA + gsl      : Em1;
        int jA1 = dA ? iA + 8 + gsl  : Em1;
        int jA2 = dA ? iA + 16 + gsl : Em1;
        int jA3 = dA ? iA + 24 + gsl : Em1;
        int jB0 = dB ? iB + gsl      : Em1;
        int jB1 = dB ? iB + 8 + gsl  : Em1;
        int jB2 = dB ? iB + 16 + gsl : Em1;
        int jB3 = dB ? iB + 24 + gsl : Em1;
        int sA0 = csr[jA0], sA1 = csr[jA1], sA2 = csr[jA2], sA3 = csr[jA3];
        int sB0 = csr[jB0], sB1 = csr[jB1], sB2 = csr[jB2], sB3 = csr[jB3];
        uint4 vA0 = *(const uint4*)(g3 + (size_t)sA0 * GP + base);
        uint4 vA1 = *(const uint4*)(g3 + (size_t)sA1 * GP + base);
        uint4 vA2 = *(const uint4*)(g3 + (size_t)sA2 * GP + base);
        uint4 vA3 = *(const uint4*)(g3 + (size_t)sA3 * GP + base);
        uint4 vB0 = *(const uint4*)(g3 + (size_t)sB0 * GP + base);
        uint4 vB1 = *(const uint4*)(g3 + (size_t)sB1 * GP + base);
        uint4 vB2 = *(const uint4*)(g3 + (size_t)sB2 * GP + base);
        uint4 vB3 = *(const uint4*)(g3 + (size_t)sB3 * GP + base);
        vA0 = selz(dA, vA0); vA1 = selz(dA, vA1); vA2 = selz(dA, vA2); vA3 = selz(dA, vA3);
        vB0 = selz(dB, vB0); vB1 = selz(dB, vB1); vB2 = selz(dB, vB2); vB3 = selz(dB, vB3);
        acc8(a, vA0); acc8(a, vA1); acc8(a, vA2); acc8(a, vA3);
        acc8(y, vB0); acc8(y, vB1); acc8(y, vB2); acc8(y, vB3);
        iA += dA ? 32 : 0;
        iB += dB ? 32 : 0;
    }
    {
        bool qA0 = iA + gsl < reA,      qB0 = iB + gsl < reB;
        bool qA1 = iA + 8 + gsl < reA,  qB1 = iB + 8 + gsl < reB;
        bool qA2 = iA + 16 + gsl < reA, qB2 = iB + 16 + gsl < reB;
        bool qA3 = iA + 24 + gsl < reA, qB3 = iB + 24 + gsl < reB;
        int jA0 = qA0 ? iA + gsl      : Em1;
        int jA1 = qA1 ? iA + 8 + gsl  : Em1;
        int jA2 = qA2 ? iA + 16 + gsl : Em1;
        int jA3 = qA3 ? iA + 24 + gsl : Em1;
        int jB0 = qB0 ? iB + gsl      : Em1;
        int jB1 = qB1 ? iB + 8 + gsl  : Em1;
        int jB2 = qB2 ? iB + 16 + gsl : Em1;
        int jB3 = qB3 ? iB + 24 + gsl : Em1;
        int sA0 = csr[jA0], sA1 = csr[jA1], sA2 = csr[jA2], sA3 = csr[jA3];
        int sB0 = csr[jB0], sB1 = csr[jB1], sB2 = csr[jB2], sB3 = csr[jB3];
        uint4 vA0 = *(const uint4*)(g3 + (size_t)sA0 * GP + base);
        uint4 vA1 = *(const uint4*)(g3 + (size_t)sA1 * GP + base);
        uint4 vA2 = *(const uint4*)(g3 + (size_t)sA2 * GP + base);
        uint4 vA3 = *(const uint4*)(g3 + (size_t)sA3 * GP + base);
        uint4 vB0 = *(const uint4*)(g3 + (size_t)sB0 * GP + base);
        uint4 vB1 = *(const uint4*)(g3 + (size_t)sB1 * GP + base);
        uint4 vB2 = *(const uint4*)(g3 + (size_t)sB2 * GP + base);
        uint4 vB3 = *(const uint4*)(g3 + (size_t)sB3 * GP + base);
        vA0 = selz(qA0, vA0); vA1 = selz(qA1, vA1); vA2 = selz(qA2, vA2); vA3 = selz(qA3, vA3);
        vB0 = selz(qB0, vB0); vB1 = selz(qB1, vB1); vB2 = selz(qB2, vB2); vB3 = selz(qB3, vB3);
        acc8(a, vA0); acc8(a, vA1); acc8(a, vA2); acc8(a, vA3);
        acc8(y, vB0); acc8(y, vB1); acc8(y, vB2); acc8(y, vB3);
    }
    uint4 svA = *(const uint4*)(g3 + (size_t)nA * GP + base);
    uint4 svB = *(const uint4*)(g3 + (size_t)nB * GP + base);
#pragma unroll
    for (int j = 0; j < 8; ++j) a[j] += __shfl_xor(a[j], 8);
#pragma unroll
    for (int j = 0; j < 8; ++j) a[j] += __shfl_xor(a[j], 16);
#pragma unroll
    for (int j = 0; j < 8; ++j) a[j] += __shfl_xor(a[j], 32);
#pragma unroll
    for (int j = 0; j < 8; ++j) y[j] += __shfl_xor(y[j], 8);
#pragma unroll
    for (int j = 0; j < 8; ++j) y[j] += __shfl_xor(y[j], 16);
#pragma unroll
    for (int j = 0; j < 8; ++j) y[j] += __shfl_xor(y[j], 32);
    acc8(a, svA);
    acc8(y, svB);
    float2 dv2 = *(const float2*)(dinv + nA);
    float dv = (gsl == 0) ? dv2.x : dv2.y;
    float s[8];
#pragma unroll
    for (int j = 0; j < 8; ++j) s[j] = (gsl == 0) ? a[j] : y[j];
    float z[8];
    if (c < 5) {
        float4 bb0 = *(const float4*)(b3 + base);
        float4 bb1 = *(const float4*)(b3 + base + 4);
        z[0] = s[0] * dv + bb0.x; z[1] = s[1] * dv + bb0.y;
        z[2] = s[2] * dv + bb0.z; z[3] = s[3] * dv + bb0.w;
        z[4] = s[4] * dv + bb1.x; z[5] = s[5] * dv + bb1.y;
        z[6] = s[6] * dv + bb1.z; z[7] = s[7] * dv + bb1.w;
    } else {
#pragma unroll
        for (int j = 0; j < 8; ++j) z[j] = -1e30f;
    }
    // per-gsl-group softmax over the 8 c-lanes (xor of bits 0..2 stays in group)
    float m = fmaxf(fmaxf(fmaxf(z[0], z[1]), fmaxf(z[2], z[3])),
                    fmaxf(fmaxf(z[4], z[5]), fmaxf(z[6], z[7])));
    m = fmaxf(m, __shfl_xor(m, 1));
    m = fmaxf(m, __shfl_xor(m, 2));
    m = fmaxf(m, __shfl_xor(m, 4));
    float e = 0.f;
    if (c < 5) {
#pragma unroll
        for (int j = 0; j < 8; ++j) e += __expf(z[j] - m);
    }
    e += __shfl_xor(e, 1);
    e += __shfl_xor(e, 2);
    e += __shfl_xor(e, 4);
    float ls = __logf(e);
    if (gsl < 2 && c < 5) {
        float4 o0 = { z[0] - m - ls, z[1] - m - ls, z[2] - m - ls, z[3] - m - ls };
        float4 o1 = { z[4] - m - ls, z[5] - m - ls, z[6] - m - ls, z[7] - m - ls };
        float* orow = out + (size_t)(nA + gsl) * CD + base;
        *(float4*)(orow)     = o0;
        *(float4*)(orow + 4) = o1;
    }
}

// ---------------- launcher ----------------

extern "C" void kernel_launch(void* const* d_in, const int* in_sizes, int n_in,
                              void* d_out, int out_size, void* d_ws, size_t ws_size,
                              hipStream_t stream) {
    (void)n_in; (void)out_size; (void)ws_size;
    const float* x   = (const float*)d_in[0];
    const int*   ei  = (const int*)d_in[1];
    const float* W1  = (const float*)d_in[2];
    const float* b1  = (const float*)d_in[3];
    const float* W2  = (const float*)d_in[4];
    const float* b2  = (const float*)d_in[5];
    const float* W3  = (const float*)d_in[6];
    const float* b3  = (const float*)d_in[7];
    const float* g1  = (const float*)d_in[8];
    const float* bt1 = (const float*)d_in[9];
    const float* rm1 = (const float*)d_in[10];
    const float* rv1 = (const float*)d_in[11];
    const float* g2  = (const float*)d_in[12];
    const float* bt2 = (const float*)d_in[13];
    const float* rm2 = (const float*)d_in[14];
    const float* rv2 = (const float*)d_in[15];
    float* out = (float*)d_out;
    const int E = in_sizes[1] / 2;

    char* w = (char*)d_ws;
    auto alloc = [&](size_t bytes) { char* p = w; w += (bytes + 511) & ~(size_t)511; return p; };
    int*    bcount   = (int*)alloc((size_t)NB * 4);
    int*    bstart   = (int*)alloc((size_t)(NB + 1) * 4);
    int*    bcursor  = (int*)alloc((size_t)NB * 4);
    int*    rowstart = (int*)alloc((size_t)(NN + 1) * 4);
    float*  dinv     = (float*)alloc((size_t)NN * 4);
    int*    csr      = (int*)alloc((size_t)E * 4);
    int*    ebuf     = (int*)alloc((size_t)E * 4);
    ushort* w1t      = (ushort*)alloc((size_t)H1D * FIN * 2);
    ushort* t1       = (ushort*)alloc((size_t)NN * H1D * 2);  // reused as u2
    ushort* t2       = (ushort*)alloc((size_t)NN * H1D * 2);
    ushort* g3       = (ushort*)alloc((size_t)NN * GP * 2);

    const int aggblocks = ((NN / 2) + 3) / 4;   // 2 nodes per wave, 4 waves per block

    hipMemsetAsync(bcount, 0, (size_t)NB * 4, stream);
    bhist_k<<<512, 256, 0, stream>>>(ei + E, E, bcount);
    bscan_k<<<1, 256, 0, stream>>>(bcount, bstart, bcursor);
    bscatter_k<<<(E + CHUNK - 1) / CHUNK, 256, 0, stream>>>(ei, ei + E, E, bcursor, ebuf);
    bcsr_k<<<NB, 256, 0, stream>>>(ebuf, bstart, rowstart, dinv, csr, E);
    w1cvt_k<<<(FIN * H1D + 255) / 256, 256, 0, stream>>>(W1, w1t);
    gemm1_k<<<(NN + 63) / 64, 256, 0, stream>>>(x, w1t, dinv, t1);
    agg64_k<1><<<aggblocks, 256, 0, stream>>>(t1, t2, rowstart, csr, dinv, g1, bt1, rm1, rv1, b1, E);
    agg64_k<2><<<aggblocks, 256, 0, stream>>>(t2, t1, rowstart, csr, dinv, nullptr, nullptr, nullptr, nullptr, nullptr, E);
    p2p3_k<<<(NN + 255) / 256, 256, 0, stream>>>(t1, W2, b2, W3, g2, bt2, rm2, rv2, dinv, g3);
    agg40_k<<<aggblocks, 256, 0, stream>>>(g3, b3, rowstart, csr, dinv, out, E);
}